// Round 1
// baseline (379.920 us; speedup 1.0000x reference)
//
#include <hip/hip_runtime.h>

// CostMapLayer: scatter-min of 4M points into B*512*512 cells + per-cell count.
// 3 kernels: init workspace, atomic scatter, finalize/decode.

__device__ __forceinline__ unsigned f2ord(float f) {
    // order-preserving map float -> uint (ascending). No NaNs in input.
    unsigned u = __float_as_uint(f);
    return (u & 0x80000000u) ? ~u : (u | 0x80000000u);
}
__device__ __forceinline__ float ord2f(unsigned u) {
    return __uint_as_float((u & 0x80000000u) ? (u & 0x7FFFFFFFu) : ~u);
}

__global__ void cm_init(uint2* __restrict__ cells, int nseg) {
    int i = blockIdx.x * blockDim.x + threadIdx.x;
    int stride = gridDim.x * blockDim.x;
    for (; i < nseg; i += stride)
        cells[i] = make_uint2(0xFFFFFFFFu, 0u);   // key = +inf-ish, count = 0
}

__global__ void cm_scatter(const float2* __restrict__ pts,
                           const float* __restrict__ costs,
                           uint2* __restrict__ cells,
                           int npts, int N, int H, int W) {
    int i = blockIdx.x * blockDim.x + threadIdx.x;
    if (i >= npts) return;
    float2 p = pts[i];
    int ix = (int)floorf(p.x + 0.5f);   // HALF_CENTOR = True
    int iy = (int)floorf(p.y + 0.5f);
    if (ix < 0 || ix >= W || iy < 0 || iy >= H) return;
    int b = i / N;
    int cell = (b * H + iy) * W + ix;
    unsigned key = f2ord(costs[i]);
    atomicMin(&cells[cell].x, key);   // same cacheline as the count
    atomicAdd(&cells[cell].y, 1u);
}

__global__ void cm_finalize(const uint2* __restrict__ cells,
                            const float* __restrict__ def,
                            float* __restrict__ out_cost,
                            float* __restrict__ out_mask, int nseg) {
    int i = blockIdx.x * blockDim.x + threadIdx.x;
    if (i >= nseg) return;
    uint2 c = cells[i];
    float d = *def;                     // scalar, L2-broadcast
    out_cost[i] = (c.y > 0u) ? ord2f(c.x) : d;
    out_mask[i] = (float)((int)c.y - 1);   // count-1, exact in fp32
}

extern "C" void kernel_launch(void* const* d_in, const int* in_sizes, int n_in,
                              void* d_out, int out_size, void* d_ws, size_t ws_size,
                              hipStream_t stream) {
    const float2* pts  = (const float2*)d_in[0];   // [B,N,2] f32
    const float*  cst  = (const float*)d_in[1];    // [B,N]   f32
    const float*  def  = (const float*)d_in[2];    // scalar  f32
    // d_in[3]=height, d_in[4]=width (device int scalars; fixed at 512 by the reference)
    constexpr int H = 512, W = 512;

    int npts = in_sizes[1];        // B*N
    int nseg = out_size / 2;       // B*H*W  (d_out = [cost | mask])
    int B    = nseg / (H * W);
    int N    = npts / B;

    uint2* cells    = (uint2*)d_ws;          // nseg * 8 bytes
    float* out_cost = (float*)d_out;
    float* out_mask = out_cost + nseg;

    cm_init<<<2048, 256, 0, stream>>>(cells, nseg);
    cm_scatter<<<(npts + 255) / 256, 256, 0, stream>>>(pts, cst, cells, npts, N, H, W);
    cm_finalize<<<(nseg + 255) / 256, 256, 0, stream>>>(cells, def, out_cost, out_mask, nseg);
}